// Round 7
// baseline (432.469 us; speedup 1.0000x reference)
//
#include <hip/hip_runtime.h>
#include <hip/hip_bf16.h>

// ---------------------------------------------------------------------------
// GAT (2-layer, PyG-style) on MI355X.
// R13: R9xR10 synthesis for k_agg_l1. R10 proved head-slicing+XCD binding
//      kills the gather FETCH (221->45 MB) but wave-per-(node,head) paid 8x
//      VALU fixed costs (255us). New structure: 16-lane UNITS (4/wave), unit
//      = one (node,head), 4 edge-slots x 4 ch-groups(8ch). Per-node wave-inst
//      ~= R9 (~340) while gather stays L2-local (head = blockIdx&7 == XCD).
//      xw1b/asrc1/adst1 head-major (R10-verified gemm OUTHM + alpha). Split
//      reverted to single launch. gemm2/alpha2/agg_l2 = R9-verified.
// ---------------------------------------------------------------------------

typedef __attribute__((ext_vector_type(8)))  __bf16          bf16x8;
typedef __attribute__((ext_vector_type(8)))  unsigned short  ushort8;
typedef __attribute__((ext_vector_type(16))) float           f32x16;
typedef __attribute__((ext_vector_type(2)))  float           f32x2;

#define NEG_SLOPE 0.2f
#define EPS_GAT 1e-16f

static __device__ __forceinline__ float lrelu(float x) {
    return x > 0.0f ? x : NEG_SLOPE * x;
}
static __device__ __forceinline__ unsigned short f2bf(float f) {
    unsigned u = __float_as_uint(f);
    return (unsigned short)((u + 0x7fffu + ((u >> 16) & 1u)) >> 16);
}
static __device__ __forceinline__ float bf2f(unsigned short v) {
    return __uint_as_float(((unsigned)v) << 16);
}
// ordered-uint encoding for float atomicMax; enc(x)>0 for finite x, so
// memset-0 init acts as -inf.
static __device__ __forceinline__ unsigned encf(float x) {
    unsigned u = __float_as_uint(x);
    return (u >> 31) ? ~u : (u | 0x80000000u);
}
static __device__ __forceinline__ float decf(unsigned e) {
    unsigned u = (e >> 31) ? (e & 0x7fffffffu) : ~e;
    return __uint_as_float(u);
}

// --------------- histogram (direct eix, per-block dtype detect) ------------
__global__ void k_hist_w(const void* __restrict__ eix, int* __restrict__ counts,
                         int E, int EB,
                         const float* __restrict__ W1, const float* __restrict__ W2,
                         unsigned short* __restrict__ w1t, unsigned short* __restrict__ w2t) {
    int b = blockIdx.x;
    if (b < EB) {
        int i = b * 256 + threadIdx.x;
        unsigned w = ((const unsigned*)eix)[2 * min(i, E - 1) + 1];
        bool is64 = (__syncthreads_or((int)(w != 0u)) == 0);
        if (i < E) {
            int d = is64 ? (int)((const long long*)eix)[E + i]
                         : ((const int*)eix)[E + i];
            atomicAdd(&counts[d], 1);
        }
    } else {
        int t = (b - EB) * 256 + threadIdx.x;
        if (t < 512 * 256) {
            int k = t >> 8, m = t & 255;
            w1t[m * 512 + k] = f2bf(W1[t]);
        } else {
            int u = t - 512 * 256;
            if (u < 256 * 64) {
                int k = u >> 6, m = u & 63;
                w2t[m * 256 + k] = f2bf(W2[u]);
            }
        }
    }
}

// -------------------- hierarchical CSR scan (3 kernels) --------------------
__global__ void k_scan1(const int* __restrict__ counts, int* __restrict__ rowp,
                        int* __restrict__ bsum, int N) {
    __shared__ int s[256];
    int t = threadIdx.x, i = blockIdx.x * 256 + t;
    int v = (i < N) ? counts[i] : 0;
    s[t] = v;
    __syncthreads();
    for (int off = 1; off < 256; off <<= 1) {
        int u = (t >= off) ? s[t - off] : 0;
        __syncthreads();
        s[t] += u;
        __syncthreads();
    }
    if (i < N) rowp[i] = s[t] - v;          // exclusive within block
    if (t == 255) bsum[blockIdx.x] = s[255];
}

__global__ void k_scan2(const int* __restrict__ bsum, int* __restrict__ boff,
                        int* __restrict__ rowp_last, int NB) {
    __shared__ int s[256];
    int t = threadIdx.x;
    int v = (t < NB) ? bsum[t] : 0;
    s[t] = v;
    __syncthreads();
    for (int off = 1; off < 256; off <<= 1) {
        int u = (t >= off) ? s[t - off] : 0;
        __syncthreads();
        s[t] += u;
        __syncthreads();
    }
    if (t < NB) boff[t] = s[t] - v;
    if (t == 255) *rowp_last = s[255];      // == E
}

__global__ void k_scan3(int* __restrict__ rowp, int* __restrict__ cursor,
                        const int* __restrict__ boff, int N) {
    int i = blockIdx.x * 256 + threadIdx.x;
    if (i < N) {
        int r = rowp[i] + boff[blockIdx.x];
        rowp[i] = r;
        cursor[i] = r;
    }
}

// ------------------------ fill (direct eix reads) --------------------------
__global__ void k_fill(const void* __restrict__ eix, int* __restrict__ cursor,
                       int* __restrict__ ssrc, int E) {
    int i = blockIdx.x * 256 + threadIdx.x;
    unsigned w = ((const unsigned*)eix)[2 * min(i, E - 1) + 1];
    bool is64 = (__syncthreads_or((int)(w != 0u)) == 0);
    if (i >= E) return;
    int s, d;
    if (is64) {
        s = (int)((const long long*)eix)[i];
        d = (int)((const long long*)eix)[E + i];
    } else {
        s = ((const int*)eix)[i];
        d = ((const int*)eix)[E + i];
    }
    int pos = atomicAdd(&cursor[d], 1);
    ssrc[pos] = s;
}

// ------------------------------- bf16 GEMM ---------------------------------
// T14 reg-staged pipeline (R9). OUTHM stores C head-major:
// [col>>5][row][col&31] (32-ch head groups) -- verified in R10.
template <int BM, int BN, int NT, bool AF32, bool OUTBF, bool OUTHM>
__global__ __launch_bounds__(NT) void k_gemm(const void* __restrict__ Ain,
                                             const unsigned short* __restrict__ Bt,
                                             void* __restrict__ Cout, int Nrows, int K) {
    constexpr int LD = 40;
    constexpr int AIT = BM * 4 / NT;   // ushort8 items of A per thread
    constexpr int BIT = BN * 4 / NT;   // ushort8 items of B per thread
    __shared__ __align__(16) unsigned short As[BM * LD];
    __shared__ __align__(16) unsigned short Bs[BN * LD];
    const int tid = threadIdx.x;
    const int blockRow = blockIdx.x * BM;
    const int wave = tid >> 6, lane = tid & 63;
    constexpr int WR = BM / 64;
    const int wr = wave % WR, wc = wave / WR;
    const int m = lane & 31;
    const int ksel = (lane >> 5) * 8;

    f32x16 acc00{}, acc01{}, acc10{}, acc11{};

    // register prefetch state
    float4  af0[AIT], af1[AIT];   // AF32 path
    ushort8 ab[AIT];              // bf16 path
    ushort8 bb[BIT];

    auto loadA = [&](int kt) {
        #pragma unroll
        for (int i = 0; i < AIT; ++i) {
            int idx = tid + i * NT;
            int r = idx >> 2, kc = (idx & 3) * 8;
            int grow = blockRow + r;
            if constexpr (AF32) {
                const float* A = (const float*)Ain;
                if (grow < Nrows) {
                    const float* ap = A + (size_t)grow * K + kt + kc;
                    af0[i] = *(const float4*)ap;
                    af1[i] = *(const float4*)(ap + 4);
                } else {
                    af0[i] = make_float4(0.f, 0.f, 0.f, 0.f);
                    af1[i] = make_float4(0.f, 0.f, 0.f, 0.f);
                }
            } else {
                const unsigned short* A = (const unsigned short*)Ain;
                ushort8 o{};
                if (grow < Nrows) o = *(const ushort8*)(A + (size_t)grow * K + kt + kc);
                ab[i] = o;
            }
        }
    };
    auto loadB = [&](int kt) {
        #pragma unroll
        for (int i = 0; i < BIT; ++i) {
            int idx = tid + i * NT;
            int r = idx >> 2, kc = (idx & 3) * 8;
            bb[i] = *(const ushort8*)(Bt + (size_t)r * K + kt + kc);
        }
    };
    auto writeAB = [&]() {
        #pragma unroll
        for (int i = 0; i < AIT; ++i) {
            int idx = tid + i * NT;
            int r = idx >> 2, kc = (idx & 3) * 8;
            if constexpr (AF32) {
                union { ushort8 u; __hip_bfloat162 h[4]; } cv;
                cv.h[0] = __float22bfloat162_rn(make_float2(af0[i].x, af0[i].y));
                cv.h[1] = __float22bfloat162_rn(make_float2(af0[i].z, af0[i].w));
                cv.h[2] = __float22bfloat162_rn(make_float2(af1[i].x, af1[i].y));
                cv.h[3] = __float22bfloat162_rn(make_float2(af1[i].z, af1[i].w));
                *(ushort8*)&As[r * LD + kc] = cv.u;
            } else {
                *(ushort8*)&As[r * LD + kc] = ab[i];
            }
        }
        #pragma unroll
        for (int i = 0; i < BIT; ++i) {
            int idx = tid + i * NT;
            int r = idx >> 2, kc = (idx & 3) * 8;
            *(ushort8*)&Bs[r * LD + kc] = bb[i];
        }
    };

    loadA(0);
    loadB(0);
    for (int kt = 0; kt < K; kt += 32) {
        writeAB();
        __syncthreads();
        if (kt + 32 < K) {      // issue next tile's loads; consumed next iter
            loadA(kt + 32);
            loadB(kt + 32);
        }
        #pragma unroll
        for (int kk = 0; kk < 32; kk += 16) {
            bf16x8 a0 = *(const bf16x8*)&As[(wr * 64 +      m) * LD + kk + ksel];
            bf16x8 a1 = *(const bf16x8*)&As[(wr * 64 + 32 + m) * LD + kk + ksel];
            bf16x8 b0 = *(const bf16x8*)&Bs[(wc * 64 +      m) * LD + kk + ksel];
            bf16x8 b1 = *(const bf16x8*)&Bs[(wc * 64 + 32 + m) * LD + kk + ksel];
            acc00 = __builtin_amdgcn_mfma_f32_32x32x16_bf16(a0, b0, acc00, 0, 0, 0);
            acc01 = __builtin_amdgcn_mfma_f32_32x32x16_bf16(a0, b1, acc01, 0, 0, 0);
            acc10 = __builtin_amdgcn_mfma_f32_32x32x16_bf16(a1, b0, acc10, 0, 0, 0);
            acc11 = __builtin_amdgcn_mfma_f32_32x32x16_bf16(a1, b1, acc11, 0, 0, 0);
        }
        __syncthreads();
    }

    const int dcol = wc * 64 + (lane & 31);
    const int dquad = 4 * (lane >> 5);
    auto store_tile = [&](const f32x16& a, int rt, int ct) {
        #pragma unroll
        for (int r = 0; r < 16; ++r) {
            int row = blockRow + wr * 64 + rt * 32 + (r & 3) + 8 * (r >> 2) + dquad;
            if (row < Nrows) {
                int col = dcol + ct * 32;
                size_t off;
                if constexpr (OUTHM)
                    off = ((size_t)(col >> 5) * Nrows + row) * 32 + (col & 31);
                else
                    off = (size_t)row * BN + col;
                if constexpr (OUTBF) ((unsigned short*)Cout)[off] = f2bf(a[r]);
                else                 ((float*)Cout)[off] = a[r];
            }
        }
    };
    store_tile(acc00, 0, 0); store_tile(acc01, 0, 1);
    store_tile(acc10, 1, 0); store_tile(acc11, 1, 1);
}

// ----------- attention logits + global head max (atomicMax enc) ------------
// xw is HEAD-MAJOR [H][Nn][C]; os/od written head-major [H][Nn]. (R10-verified;
// for H=1 identical to node-major.)
__global__ void k_alpha(const unsigned short* __restrict__ xw, const float* __restrict__ a_s,
                        const float* __restrict__ a_d, float* __restrict__ os,
                        float* __restrict__ od, unsigned* __restrict__ Menc,
                        int NH, int H, int C, int Nn) {
    __shared__ float red[256];
    int t = blockIdx.x * 256 + threadIdx.x;
    float s = -1e30f, d = 0.f;
    if (t < NH) {
        int n = t / H, h = t - n * H;
        const unsigned short* row = xw + ((size_t)h * Nn + n) * C;
        s = 0.f;
        for (int c = 0; c < C; c += 8) {
            ushort8 v = *(const ushort8*)(row + c);
            #pragma unroll
            for (int q = 0; q < 8; ++q) {
                float f = bf2f(v[q]);
                s += f * a_s[h * C + c + q];
                d += f * a_d[h * C + c + q];
            }
        }
        size_t oi = (size_t)h * Nn + n;
        os[oi] = s; od[oi] = d;
    }
    red[threadIdx.x] = s;
    __syncthreads();
    for (int off = 128; off >= H; off >>= 1) {
        if (threadIdx.x < off) red[threadIdx.x] = fmaxf(red[threadIdx.x], red[threadIdx.x + off]);
        __syncthreads();
    }
    if ((int)threadIdx.x < H) atomicMax(&Menc[threadIdx.x], encf(red[threadIdx.x]));
}

// ---- layer 1: 16-lane units, unit = (node, head); 4 units/wave ------------
// head = blockIdx&7 == XCD (round-robin dispatch) -> per-XCD L2 caches only
// its 3.2 MB head slice of xwh: gather is L2-resident (R10's locality) while
// per-node wave-inst count stays ~R9 (4 (node,head) units share each wave
// instruction; reduce is 2 shuffle steps over edge-slot lane bits 2,3).
// Unit lanes: e = (lane&15)>>2 edge slot (4 edges/iter), c8 = (lane&3)*8.
__global__ __launch_bounds__(256, 6) void k_agg_l1(
        const unsigned short* __restrict__ xwh,   // [8][N][32] bf16
        const float* __restrict__ asrc,           // [8][N]
        const float* __restrict__ adst,           // [8][N]
        const unsigned* __restrict__ Menc,
        const float* __restrict__ b1, const int* __restrict__ rp,
        const int* __restrict__ ssrc, unsigned short* __restrict__ hbf, int N) {
    const int h = blockIdx.x & 7;
    const int n = (int)(blockIdx.x >> 3) * 16 + (threadIdx.x >> 4);
    if (n >= N) return;
    const int l  = threadIdx.x & 15;
    const int e  = l >> 2;          // edge slot within unit
    const int c8 = (l & 3) * 8;     // channel offset (8 ch per lane)
    const size_t hN = (size_t)h * N;
    const float ad = adst[hN + n];
    const float m  = lrelu(decf(Menc[h]) + ad);   // >= all edge logits (lrelu monotone)
    f32x2 acc[4];
    float s;
    {   // self loop counted on edge-slot 0 only
        float w = (e == 0) ? __expf(lrelu(asrc[hN + n] + ad) - m) : 0.0f;
        ushort8 xv = *(const ushort8*)(xwh + (hN + n) * 32 + c8);
        s = w;
        const unsigned* dx = (const unsigned*)&xv;
        #pragma unroll
        for (int p = 0; p < 4; ++p) {
            acc[p].x = w * __uint_as_float(dx[p] << 16);
            acc[p].y = w * __uint_as_float(dx[p] & 0xffff0000u);
        }
    }
    const int e0 = rp[n], e1 = rp[n + 1];
    if (e0 < e1) {
        const int NQ = (e1 - e0 + 3) >> 2;    // quads of 4 edges

        auto LDJ = [&](int base, int& j, bool& v) {
            v = base + e < e1;
            j = ssrc[min(base + e, e1 - 1)];
        };
        auto LDD = [&](int j, float& as, ushort8& xv) {
            as = asrc[hN + j];
            xv = *(const ushort8*)(xwh + ((hN + j) << 5) + c8);
        };
        auto CONS = [&](bool v, float as, const ushort8& xv) {
            float w = v ? __expf(lrelu(as + ad) - m) : 0.0f;
            s += w;
            f32x2 wp; wp.x = w; wp.y = w;
            const unsigned* dx = (const unsigned*)&xv;
            #pragma unroll
            for (int p = 0; p < 4; ++p) {
                f32x2 x;
                x.x = __uint_as_float(dx[p] << 16);
                x.y = __uint_as_float(dx[p] & 0xffff0000u);
                asm("v_pk_fma_f32 %0, %1, %2, %3"
                    : "=v"(acc[p]) : "v"(x), "v"(wp), "v"(acc[p]));
            }
        };

        // 4-deep pipeline (R9 idiom): data 2 quads in flight, indices 2 ahead
        int j0, j1, j2, j3; bool v0, v1, v2, v3;
        float as0, as1; ushort8 xv0, xv1;
        LDJ(e0,      j0, v0);
        LDJ(e0 + 4,  j1, v1);
        LDD(j0, as0, xv0);               // one unavoidable RT stall on j0
        LDJ(e0 + 8,  j2, v2);
        LDD(j1, as1, xv1);
        LDJ(e0 + 12, j3, v3);

        #pragma unroll 2
        for (int k = 0; k < NQ - 2; ++k) {
            int jN; bool vN;
            LDJ(e0 + 4 * k + 16, jN, vN);
            float as2; ushort8 xv2;
            LDD(j2, as2, xv2);           // quad k+2, index fetched 2 iters ago
            CONS(v0, as0, xv0);          // quad k, data in flight 2 iters
            v0 = v1; as0 = as1; xv0 = xv1;
            v1 = v2; as1 = as2; xv1 = xv2;
            v2 = v3; j2 = j3;
            v3 = vN; j3 = jN;
        }
        CONS(v0, as0, xv0);
        if (NQ >= 2) CONS(v1, as1, xv1);
    }
    // reduce over edge-slot lane bits (bit2, bit3) -- stays within the unit
    s += __shfl_xor(s, 4, 64);
    s += __shfl_xor(s, 8, 64);
    #pragma unroll
    for (int p = 0; p < 4; ++p) {
        acc[p].x += __shfl_xor(acc[p].x, 4, 64);
        acc[p].x += __shfl_xor(acc[p].x, 8, 64);
        acc[p].y += __shfl_xor(acc[p].y, 4, 64);
        acc[p].y += __shfl_xor(acc[p].y, 8, 64);
    }
    if (e == 0) {   // lanes l=0..3 hold channels c8..c8+7
        float inv = 1.0f / (s + EPS_GAT);
        int fb = h * 32 + c8;
        ushort8 o;
        #pragma unroll
        for (int p = 0; p < 4; ++p) {
            float v0 = acc[p].x * inv + b1[fb + 2 * p];
            float v1 = acc[p].y * inv + b1[fb + 2 * p + 1];
            v0 = v0 > 0.f ? v0 : expm1f(v0);
            v1 = v1 > 0.f ? v1 : expm1f(v1);
            ((unsigned short*)&o)[2 * p]     = f2bf(v0);
            ((unsigned short*)&o)[2 * p + 1] = f2bf(v1);
        }
        *(ushort8*)(hbf + (size_t)n * 256 + fb) = o;   // hbf node-major (gemm2 A)
    }
}

// ---- layer 2: 8 edges/wave, branchless 4-deep pipeline + log_softmax ------
// g = lane>>3 picks edge of octet; q = lane&7 holds classes [q*8, q*8+8)
__global__ __launch_bounds__(256, 6) void k_agg_l2(
        const unsigned short* __restrict__ xw2, const float* __restrict__ asrc,
        const float* __restrict__ adst, const unsigned* __restrict__ Menc,
        const float* __restrict__ b2, const int* __restrict__ rp,
        const int* __restrict__ ssrc, float* __restrict__ out, int N) {
    int wid = (blockIdx.x * 256 + threadIdx.x) >> 6;
    if (wid >= N) return;
    const int lane = threadIdx.x & 63;
    const int g  = lane >> 3;
    const int q  = lane & 7;
    const int f0 = q * 8;
    const float ad = adst[wid];
    const float m = lrelu(decf(Menc[0]) + ad);
    f32x2 acc[4];
    float s;
    {   // self loop counted on group 0 only
        float w = (g == 0) ? __expf(lrelu(asrc[wid] + ad) - m) : 0.0f;
        ushort8 xv = *(const ushort8*)(xw2 + (size_t)wid * 64 + f0);
        s = w;
        const unsigned* dx = (const unsigned*)&xv;
        #pragma unroll
        for (int p = 0; p < 4; ++p) {
            acc[p].x = w * __uint_as_float(dx[p] << 16);
            acc[p].y = w * __uint_as_float(dx[p] & 0xffff0000u);
        }
    }
    const int e0 = rp[wid], e1 = rp[wid + 1];
    if (e0 < e1) {
        const int NQ = (e1 - e0 + 7) >> 3;

        auto LDJ = [&](int base, int& j, bool& v) {
            v = base + g < e1;
            j = ssrc[min(base + g, e1 - 1)];
        };
        auto LDD = [&](int j, float& as, ushort8& xv) {
            as = asrc[j];
            xv = *(const ushort8*)(xw2 + ((size_t)j << 6) + f0);
        };
        auto CONS = [&](bool v, float as, const ushort8& xv) {
            float w = v ? __expf(lrelu(as + ad) - m) : 0.0f;
            s += w;
            f32x2 wp; wp.x = w; wp.y = w;
            const unsigned* dx = (const unsigned*)&xv;
            #pragma unroll
            for (int p = 0; p < 4; ++p) {
                f32x2 x;
                x.x = __uint_as_float(dx[p] << 16);
                x.y = __uint_as_float(dx[p] & 0xffff0000u);
                asm("v_pk_fma_f32 %0, %1, %2, %3"
                    : "=v"(acc[p]) : "v"(x), "v"(wp), "v"(acc[p]));
            }
        };

        int j0, j1, j2, j3; bool v0, v1, v2, v3;
        float as0, as1; ushort8 xv0, xv1;
        LDJ(e0,      j0, v0);
        LDJ(e0 + 8,  j1, v1);
        LDD(j0, as0, xv0);
        LDJ(e0 + 16, j2, v2);
        LDD(j1, as1, xv1);
        LDJ(e0 + 24, j3, v3);

        #pragma unroll 2
        for (int k = 0; k < NQ - 2; ++k) {
            int jN; bool vN;
            LDJ(e0 + 8 * k + 32, jN, vN);
            float as2; ushort8 xv2;
            LDD(j2, as2, xv2);
            CONS(v0, as0, xv0);
            v0 = v1; as0 = as1; xv0 = xv1;
            v1 = v2; as1 = as2; xv1 = xv2;
            v2 = v3; j2 = j3;
            v3 = vN; j3 = jN;
        }
        CONS(v0, as0, xv0);
        if (NQ >= 2) CONS(v1, as1, xv1);
    }
    // combine the 8 edge-groups (group id in lane bits 3..5)
    s += __shfl_xor(s, 8, 64);
    s += __shfl_xor(s, 16, 64);
    s += __shfl_xor(s, 32, 64);
    #pragma unroll
    for (int p = 0; p < 4; ++p) {
        acc[p].x += __shfl_xor(acc[p].x, 8, 64);
        acc[p].x += __shfl_xor(acc[p].x, 16, 64);
        acc[p].x += __shfl_xor(acc[p].x, 32, 64);
        acc[p].y += __shfl_xor(acc[p].y, 8, 64);
        acc[p].y += __shfl_xor(acc[p].y, 16, 64);
        acc[p].y += __shfl_xor(acc[p].y, 32, 64);
    }
    float inv = 1.0f / (s + EPS_GAT);
    float val[8];
    float mx = -1e30f;
    #pragma unroll
    for (int i = 0; i < 8; ++i) {
        float a = (i & 1) ? acc[i >> 1].y : acc[i >> 1].x;
        val[i] = a * inv + b2[f0 + i];
        mx = fmaxf(mx, val[i]);
    }
    // class reduce across q lanes (bits 0..2)
    #pragma unroll
    for (int off = 4; off > 0; off >>= 1) mx = fmaxf(mx, __shfl_xor(mx, off, 64));
    float sm = 0.f;
    #pragma unroll
    for (int i = 0; i < 8; ++i) sm += __expf(val[i] - mx);
    #pragma unroll
    for (int off = 4; off > 0; off >>= 1) sm += __shfl_xor(sm, off, 64);
    float lse = mx + logf(sm);
    if (g == 0) {
        float4 o0 = make_float4(val[0] - lse, val[1] - lse, val[2] - lse, val[3] - lse);
        float4 o1 = make_float4(val[4] - lse, val[5] - lse, val[6] - lse, val[7] - lse);
        *(float4*)(out + (size_t)wid * 64 + f0)     = o0;
        *(float4*)(out + (size_t)wid * 64 + f0 + 4) = o1;
    }
}

// ------------------------------- launcher ----------------------------------
static inline int cdiv(int a, int b) { return (a + b - 1) / b; }

extern "C" void kernel_launch(void* const* d_in, const int* in_sizes, int n_in,
                              void* d_out, int out_size, void* d_ws, size_t ws_size,
                              hipStream_t stream) {
    const float* x   = (const float*)d_in[0];
    const void*  eix = d_in[1];
    const float* W1  = (const float*)d_in[2];
    const float* as1 = (const float*)d_in[3];
    const float* ad1 = (const float*)d_in[4];
    const float* b1  = (const float*)d_in[5];
    const float* W2  = (const float*)d_in[6];
    const float* as2 = (const float*)d_in[7];
    const float* ad2 = (const float*)d_in[8];
    const float* b2  = (const float*)d_in[9];
    float* out = (float*)d_out;

    const int N = in_sizes[0] / 512;
    const int E = in_sizes[1] / 2;
    const int EB = cdiv(E, 256);
    const int WB = cdiv(512 * 256 + 256 * 64, 256);
    const int NB = cdiv(N, 256);
    const int NB1 = cdiv(N * 8, 256);
    const int NB2 = cdiv(N, 256);
    (void)n_in; (void)out_size; (void)ws_size;

    char* base = (char*)d_ws;
    size_t o = 0;
    auto alloc = [&](size_t bytes) -> char* {
        o = (o + 255) & ~(size_t)255;
        char* p = base + o;
        o += bytes;
        return p;
    };
    unsigned short* xw1b  = (unsigned short*)alloc((size_t)N * 256 * 2);  // head-major [8][N][32]
    unsigned short* hbf   = (unsigned short*)alloc((size_t)N * 256 * 2);  // node-major
    unsigned short* xw2b  = (unsigned short*)alloc((size_t)N * 64 * 2);
    float*          asrc1 = (float*)alloc((size_t)N * 8 * 4);             // head-major [8][N]
    float*          adst1 = (float*)alloc((size_t)N * 8 * 4);             // head-major [8][N]
    float*          asrc2 = (float*)alloc((size_t)N * 4);
    float*          adst2 = (float*)alloc((size_t)N * 4);
    // zero region: Menc + counts contiguous, one memset
    size_t zero_begin = (o + 255) & ~(size_t)255;
    unsigned*       Menc  = (unsigned*)alloc(16 * 4);   // [0..7]=L1 heads, [8]=L2
    int*            counts= (int*)alloc((size_t)N * 4);
    size_t zero_end = o;
    int*            cursor= (int*)alloc((size_t)N * 4);
    int*            rowp  = (int*)alloc((size_t)(N + 1) * 4);
    int*            bsum  = (int*)alloc(256 * 4);
    int*            boff  = (int*)alloc(256 * 4);
    unsigned short* w1t   = (unsigned short*)alloc(512 * 256 * 2);
    unsigned short* w2t   = (unsigned short*)alloc(256 * 64 * 2);
    int*            ssrc  = (int*)alloc((size_t)E * 4);

    hipMemsetAsync(base + zero_begin, 0, zero_end - zero_begin, stream);

    // CSR build + weight prep folded into histogram grid
    k_hist_w<<<EB + WB, 256, 0, stream>>>(eix, counts, E, EB, W1, W2, w1t, w2t);
    k_scan1<<<NB, 256, 0, stream>>>(counts, rowp, bsum, N);
    k_scan2<<<1, 256, 0, stream>>>(bsum, boff, rowp + N, NB);
    k_scan3<<<NB, 256, 0, stream>>>(rowp, cursor, boff, N);
    k_fill<<<EB, 256, 0, stream>>>(eix, cursor, ssrc, E);

    // layer 1 (xw1b head-major; agg units (node,head), head == blockIdx&7 == XCD)
    k_gemm<128, 256, 512, true, true, true><<<cdiv(N, 128), 512, 0, stream>>>(x, w1t, xw1b, N, 512);
    k_alpha<<<NB1, 256, 0, stream>>>(xw1b, as1, ad1, asrc1, adst1, Menc, N * 8, 8, 32, N);
    k_agg_l1<<<cdiv(N, 16) * 8, 256, 0, stream>>>(xw1b, asrc1, adst1, Menc, b1,
                                                  rowp, ssrc, hbf, N);
    // layer 2 (H=1: head-major == node-major everywhere)
    k_gemm<256, 64, 256, false, true, false><<<cdiv(N, 256), 256, 0, stream>>>(hbf, w2t, xw2b, N, 256);
    k_alpha<<<NB2, 256, 0, stream>>>(xw2b, as2, ad2, asrc2, adst2, Menc + 8, N, 1, 64, N);
    k_agg_l2<<<cdiv(N * 64, 256), 256, 0, stream>>>(xw2b, asrc2, adst2, Menc + 8, b2,
                                                    rowp, ssrc, out, N);
}

// Round 8
// 412.584 us; speedup vs baseline: 1.0482x; 1.0482x over previous
//
#include <hip/hip_runtime.h>
#include <hip/hip_bf16.h>

// ---------------------------------------------------------------------------
// GAT (2-layer, PyG-style) on MI355X.
// R14: clean rerun of R11's concurrency experiment. R13 (16-lane units +
//      head-major) fixed FETCH (47 MB) but is VALU-bound at 94us (97% busy,
//      4x exp redundancy + per-unit fixed costs) -> R9 structure stays.
//      R11's 5-stage agg_l1 (3 gather-quads in flight) was invalidated by
//      launch_bounds(256,8) -> VGPR cap 32 -> 629 MB scratch spill. Same
//      pipeline now under launch_bounds(256,6) (VGPR budget 85, needs ~65).
//      Everything else = R9-verified (416.7us; gemm T14, agg_l2, alpha).
//      Checks: WRITE_SIZE ~25 MB (no spill), agg_l1 60-66us if concurrency-
//      limited / 76us if fabric-ceiling.
// ---------------------------------------------------------------------------

typedef __attribute__((ext_vector_type(8)))  __bf16          bf16x8;
typedef __attribute__((ext_vector_type(8)))  unsigned short  ushort8;
typedef __attribute__((ext_vector_type(16))) float           f32x16;
typedef __attribute__((ext_vector_type(2)))  float           f32x2;

#define NEG_SLOPE 0.2f
#define EPS_GAT 1e-16f

static __device__ __forceinline__ float lrelu(float x) {
    return x > 0.0f ? x : NEG_SLOPE * x;
}
static __device__ __forceinline__ unsigned short f2bf(float f) {
    unsigned u = __float_as_uint(f);
    return (unsigned short)((u + 0x7fffu + ((u >> 16) & 1u)) >> 16);
}
static __device__ __forceinline__ float bf2f(unsigned short v) {
    return __uint_as_float(((unsigned)v) << 16);
}
// ordered-uint encoding for float atomicMax; enc(x)>0 for finite x, so
// memset-0 init acts as -inf.
static __device__ __forceinline__ unsigned encf(float x) {
    unsigned u = __float_as_uint(x);
    return (u >> 31) ? ~u : (u | 0x80000000u);
}
static __device__ __forceinline__ float decf(unsigned e) {
    unsigned u = (e >> 31) ? (e & 0x7fffffffu) : ~e;
    return __uint_as_float(u);
}

// --------------- histogram (direct eix, per-block dtype detect) ------------
__global__ void k_hist_w(const void* __restrict__ eix, int* __restrict__ counts,
                         int E, int EB,
                         const float* __restrict__ W1, const float* __restrict__ W2,
                         unsigned short* __restrict__ w1t, unsigned short* __restrict__ w2t) {
    int b = blockIdx.x;
    if (b < EB) {
        int i = b * 256 + threadIdx.x;
        unsigned w = ((const unsigned*)eix)[2 * min(i, E - 1) + 1];
        bool is64 = (__syncthreads_or((int)(w != 0u)) == 0);
        if (i < E) {
            int d = is64 ? (int)((const long long*)eix)[E + i]
                         : ((const int*)eix)[E + i];
            atomicAdd(&counts[d], 1);
        }
    } else {
        int t = (b - EB) * 256 + threadIdx.x;
        if (t < 512 * 256) {
            int k = t >> 8, m = t & 255;
            w1t[m * 512 + k] = f2bf(W1[t]);
        } else {
            int u = t - 512 * 256;
            if (u < 256 * 64) {
                int k = u >> 6, m = u & 63;
                w2t[m * 256 + k] = f2bf(W2[u]);
            }
        }
    }
}

// -------------------- hierarchical CSR scan (3 kernels) --------------------
__global__ void k_scan1(const int* __restrict__ counts, int* __restrict__ rowp,
                        int* __restrict__ bsum, int N) {
    __shared__ int s[256];
    int t = threadIdx.x, i = blockIdx.x * 256 + t;
    int v = (i < N) ? counts[i] : 0;
    s[t] = v;
    __syncthreads();
    for (int off = 1; off < 256; off <<= 1) {
        int u = (t >= off) ? s[t - off] : 0;
        __syncthreads();
        s[t] += u;
        __syncthreads();
    }
    if (i < N) rowp[i] = s[t] - v;          // exclusive within block
    if (t == 255) bsum[blockIdx.x] = s[255];
}

__global__ void k_scan2(const int* __restrict__ bsum, int* __restrict__ boff,
                        int* __restrict__ rowp_last, int NB) {
    __shared__ int s[256];
    int t = threadIdx.x;
    int v = (t < NB) ? bsum[t] : 0;
    s[t] = v;
    __syncthreads();
    for (int off = 1; off < 256; off <<= 1) {
        int u = (t >= off) ? s[t - off] : 0;
        __syncthreads();
        s[t] += u;
        __syncthreads();
    }
    if (t < NB) boff[t] = s[t] - v;
    if (t == 255) *rowp_last = s[255];      // == E
}

__global__ void k_scan3(int* __restrict__ rowp, int* __restrict__ cursor,
                        const int* __restrict__ boff, int N) {
    int i = blockIdx.x * 256 + threadIdx.x;
    if (i < N) {
        int r = rowp[i] + boff[blockIdx.x];
        rowp[i] = r;
        cursor[i] = r;
    }
}

// ------------------------ fill (direct eix reads) --------------------------
__global__ void k_fill(const void* __restrict__ eix, int* __restrict__ cursor,
                       int* __restrict__ ssrc, int E) {
    int i = blockIdx.x * 256 + threadIdx.x;
    unsigned w = ((const unsigned*)eix)[2 * min(i, E - 1) + 1];
    bool is64 = (__syncthreads_or((int)(w != 0u)) == 0);
    if (i >= E) return;
    int s, d;
    if (is64) {
        s = (int)((const long long*)eix)[i];
        d = (int)((const long long*)eix)[E + i];
    } else {
        s = ((const int*)eix)[i];
        d = ((const int*)eix)[E + i];
    }
    int pos = atomicAdd(&cursor[d], 1);
    ssrc[pos] = s;
}

// ------------------------------- bf16 GEMM ---------------------------------
// T14 reg-staged pipeline (R9): next K-tile's global loads issue right after
// the first barrier and are consumed (cvt+ds_write) at the top of the next
// iteration, so the vmcnt wait lands after a full compute phase.
template <int BM, int BN, int NT, bool AF32, bool OUTBF>
__global__ __launch_bounds__(NT) void k_gemm(const void* __restrict__ Ain,
                                             const unsigned short* __restrict__ Bt,
                                             void* __restrict__ Cout, int Nrows, int K) {
    constexpr int LD = 40;
    constexpr int AIT = BM * 4 / NT;   // ushort8 items of A per thread
    constexpr int BIT = BN * 4 / NT;   // ushort8 items of B per thread
    __shared__ __align__(16) unsigned short As[BM * LD];
    __shared__ __align__(16) unsigned short Bs[BN * LD];
    const int tid = threadIdx.x;
    const int blockRow = blockIdx.x * BM;
    const int wave = tid >> 6, lane = tid & 63;
    constexpr int WR = BM / 64;
    const int wr = wave % WR, wc = wave / WR;
    const int m = lane & 31;
    const int ksel = (lane >> 5) * 8;

    f32x16 acc00{}, acc01{}, acc10{}, acc11{};

    // register prefetch state
    float4  af0[AIT], af1[AIT];   // AF32 path
    ushort8 ab[AIT];              // bf16 path
    ushort8 bb[BIT];

    auto loadA = [&](int kt) {
        #pragma unroll
        for (int i = 0; i < AIT; ++i) {
            int idx = tid + i * NT;
            int r = idx >> 2, kc = (idx & 3) * 8;
            int grow = blockRow + r;
            if constexpr (AF32) {
                const float* A = (const float*)Ain;
                if (grow < Nrows) {
                    const float* ap = A + (size_t)grow * K + kt + kc;
                    af0[i] = *(const float4*)ap;
                    af1[i] = *(const float4*)(ap + 4);
                } else {
                    af0[i] = make_float4(0.f, 0.f, 0.f, 0.f);
                    af1[i] = make_float4(0.f, 0.f, 0.f, 0.f);
                }
            } else {
                const unsigned short* A = (const unsigned short*)Ain;
                ushort8 o{};
                if (grow < Nrows) o = *(const ushort8*)(A + (size_t)grow * K + kt + kc);
                ab[i] = o;
            }
        }
    };
    auto loadB = [&](int kt) {
        #pragma unroll
        for (int i = 0; i < BIT; ++i) {
            int idx = tid + i * NT;
            int r = idx >> 2, kc = (idx & 3) * 8;
            bb[i] = *(const ushort8*)(Bt + (size_t)r * K + kt + kc);
        }
    };
    auto writeAB = [&]() {
        #pragma unroll
        for (int i = 0; i < AIT; ++i) {
            int idx = tid + i * NT;
            int r = idx >> 2, kc = (idx & 3) * 8;
            if constexpr (AF32) {
                union { ushort8 u; __hip_bfloat162 h[4]; } cv;
                cv.h[0] = __float22bfloat162_rn(make_float2(af0[i].x, af0[i].y));
                cv.h[1] = __float22bfloat162_rn(make_float2(af0[i].z, af0[i].w));
                cv.h[2] = __float22bfloat162_rn(make_float2(af1[i].x, af1[i].y));
                cv.h[3] = __float22bfloat162_rn(make_float2(af1[i].z, af1[i].w));
                *(ushort8*)&As[r * LD + kc] = cv.u;
            } else {
                *(ushort8*)&As[r * LD + kc] = ab[i];
            }
        }
        #pragma unroll
        for (int i = 0; i < BIT; ++i) {
            int idx = tid + i * NT;
            int r = idx >> 2, kc = (idx & 3) * 8;
            *(ushort8*)&Bs[r * LD + kc] = bb[i];
        }
    };

    loadA(0);
    loadB(0);
    for (int kt = 0; kt < K; kt += 32) {
        writeAB();
        __syncthreads();
        if (kt + 32 < K) {      // issue next tile's loads; consumed next iter
            loadA(kt + 32);
            loadB(kt + 32);
        }
        #pragma unroll
        for (int kk = 0; kk < 32; kk += 16) {
            bf16x8 a0 = *(const bf16x8*)&As[(wr * 64 +      m) * LD + kk + ksel];
            bf16x8 a1 = *(const bf16x8*)&As[(wr * 64 + 32 + m) * LD + kk + ksel];
            bf16x8 b0 = *(const bf16x8*)&Bs[(wc * 64 +      m) * LD + kk + ksel];
            bf16x8 b1 = *(const bf16x8*)&Bs[(wc * 64 + 32 + m) * LD + kk + ksel];
            acc00 = __builtin_amdgcn_mfma_f32_32x32x16_bf16(a0, b0, acc00, 0, 0, 0);
            acc01 = __builtin_amdgcn_mfma_f32_32x32x16_bf16(a0, b1, acc01, 0, 0, 0);
            acc10 = __builtin_amdgcn_mfma_f32_32x32x16_bf16(a1, b0, acc10, 0, 0, 0);
            acc11 = __builtin_amdgcn_mfma_f32_32x32x16_bf16(a1, b1, acc11, 0, 0, 0);
        }
        __syncthreads();
    }

    const int dcol = wc * 64 + (lane & 31);
    const int dquad = 4 * (lane >> 5);
    auto store_tile = [&](const f32x16& a, int rt, int ct) {
        #pragma unroll
        for (int r = 0; r < 16; ++r) {
            int row = blockRow + wr * 64 + rt * 32 + (r & 3) + 8 * (r >> 2) + dquad;
            if (row < Nrows) {
                size_t off = (size_t)row * BN + dcol + ct * 32;
                if constexpr (OUTBF) ((unsigned short*)Cout)[off] = f2bf(a[r]);
                else                 ((float*)Cout)[off] = a[r];
            }
        }
    };
    store_tile(acc00, 0, 0); store_tile(acc01, 0, 1);
    store_tile(acc10, 1, 0); store_tile(acc11, 1, 1);
}

// ----------- attention logits + global head max (atomicMax enc) ------------
__global__ void k_alpha(const unsigned short* __restrict__ xw, const float* __restrict__ a_s,
                        const float* __restrict__ a_d, float* __restrict__ os,
                        float* __restrict__ od, unsigned* __restrict__ Menc,
                        int NH, int H, int C) {
    __shared__ float red[256];
    int t = blockIdx.x * 256 + threadIdx.x;
    float s = -1e30f, d = 0.f;
    if (t < NH) {
        int n = t / H, h = t - n * H;
        const unsigned short* row = xw + (size_t)n * H * C + h * C;
        s = 0.f;
        for (int c = 0; c < C; c += 8) {
            ushort8 v = *(const ushort8*)(row + c);
            #pragma unroll
            for (int q = 0; q < 8; ++q) {
                float f = bf2f(v[q]);
                s += f * a_s[h * C + c + q];
                d += f * a_d[h * C + c + q];
            }
        }
        os[t] = s; od[t] = d;
    }
    red[threadIdx.x] = s;
    __syncthreads();
    for (int off = 128; off >= H; off >>= 1) {
        if (threadIdx.x < off) red[threadIdx.x] = fmaxf(red[threadIdx.x], red[threadIdx.x + off]);
        __syncthreads();
    }
    if ((int)threadIdx.x < H) atomicMax(&Menc[threadIdx.x], encf(red[threadIdx.x]));
}

// ---- layer 1: 4 edges/wave, branchless 5-stage gather pipeline ------------
// g = lane>>4 picks edge of quad; q = lane&15 holds features [q*16, q*16+16)
// 3 quads of gather data in flight: D(k) resident | D(k+1), D(k+2) in
// flight | issue D(k+3) from J(k+3) | J(k+4) in flight | issue J(k+5).
// launch_bounds(256,6): VGPR budget 85 >= ~65 needed (R11's (256,8) capped
// at 32 and spilled 629 MB -- the bug this round fixes).
__global__ __launch_bounds__(256, 6) void k_agg_l1(
        const unsigned short* __restrict__ xw1, const float* __restrict__ asrc,
        const float* __restrict__ adst, const unsigned* __restrict__ Menc,
        const float* __restrict__ b1, const int* __restrict__ rp,
        const int* __restrict__ ssrc, unsigned short* __restrict__ hbf, int N) {
    int wid = (blockIdx.x * 256 + threadIdx.x) >> 6;
    if (wid >= N) return;
    const int lane = threadIdx.x & 63;
    const int g  = lane >> 4;
    const int q  = lane & 15;
    const int f0 = q * 16;
    const int h  = q >> 1;
    const int ih = wid * 8 + h;
    const float ad = adst[ih];
    const float m  = lrelu(decf(Menc[h]) + ad);   // >= all edge logits (lrelu monotone)
    f32x2 acc[8];
    float s;
    {   // self loop counted on group 0 only
        float w = (g == 0) ? __expf(lrelu(asrc[ih] + ad) - m) : 0.0f;
        const unsigned short* pr = xw1 + (size_t)wid * 256 + f0;
        ushort8 lo = *(const ushort8*)pr;
        ushort8 hi = *(const ushort8*)(pr + 8);
        s = w;
        const unsigned* dl = (const unsigned*)&lo;
        const unsigned* dh = (const unsigned*)&hi;
        #pragma unroll
        for (int p = 0; p < 4; ++p) {
            acc[p].x     = w * __uint_as_float(dl[p] << 16);
            acc[p].y     = w * __uint_as_float(dl[p] & 0xffff0000u);
            acc[4 + p].x = w * __uint_as_float(dh[p] << 16);
            acc[4 + p].y = w * __uint_as_float(dh[p] & 0xffff0000u);
        }
    }
    const int e0 = rp[wid], e1 = rp[wid + 1];
    if (e0 < e1) {
        const int NQ = (e1 - e0 + 3) >> 2;

        auto LDJ = [&](int base, int& j, bool& v) {
            v = base + g < e1;
            j = ssrc[min(base + g, e1 - 1)];
        };
        auto LDD = [&](int j, float& as, ushort8& lo, ushort8& hi) {
            as = asrc[j * 8 + h];
            const unsigned short* p = xw1 + ((size_t)j << 8) + f0;
            lo = *(const ushort8*)p;
            hi = *(const ushort8*)(p + 8);
        };
        auto CONS = [&](bool v, float as, const ushort8& lo, const ushort8& hi) {
            float w = v ? __expf(lrelu(as + ad) - m) : 0.0f;
            s += w;
            f32x2 wp; wp.x = w; wp.y = w;
            const unsigned* dl = (const unsigned*)&lo;
            const unsigned* dh = (const unsigned*)&hi;
            #pragma unroll
            for (int p = 0; p < 4; ++p) {
                f32x2 x;
                x.x = __uint_as_float(dl[p] << 16);
                x.y = __uint_as_float(dl[p] & 0xffff0000u);
                asm("v_pk_fma_f32 %0, %1, %2, %3"
                    : "=v"(acc[p]) : "v"(x), "v"(wp), "v"(acc[p]));
            }
            #pragma unroll
            for (int p = 0; p < 4; ++p) {
                f32x2 x;
                x.x = __uint_as_float(dh[p] << 16);
                x.y = __uint_as_float(dh[p] & 0xffff0000u);
                asm("v_pk_fma_f32 %0, %1, %2, %3"
                    : "=v"(acc[4 + p]) : "v"(x), "v"(wp), "v"(acc[4 + p]));
            }
        };

        // prologue: J(0..4), D(0), D(1), D(2)
        int j0, j1, j2, j3, j4; bool v0, v1, v2, v3, v4;
        float as0, as1, as2;
        ushort8 lo0, hi0, lo1, hi1, lo2, hi2;
        LDJ(e0,      j0, v0);
        LDJ(e0 + 4,  j1, v1);
        LDJ(e0 + 8,  j2, v2);
        LDD(j0, as0, lo0, hi0);          // one unavoidable RT stall on j0
        LDJ(e0 + 12, j3, v3);
        LDD(j1, as1, lo1, hi1);
        LDJ(e0 + 16, j4, v4);
        LDD(j2, as2, lo2, hi2);

        // steady state: consume quad k; D(k+1),D(k+2) in flight; issue D(k+3)
        #pragma unroll 2
        for (int k = 0; k < NQ - 3; ++k) {
            int jN; bool vN;
            LDJ(e0 + 4 * k + 20, jN, vN);
            float as3; ushort8 lo3, hi3;
            LDD(j3, as3, lo3, hi3);
            CONS(v0, as0, lo0, hi0);
            v0 = v1; as0 = as1; lo0 = lo1; hi0 = hi1;
            v1 = v2; as1 = as2; lo1 = lo2; hi1 = hi2;
            v2 = v3; as2 = as3; lo2 = lo3; hi2 = hi3;
            v3 = v4; j3 = j4;
            v4 = vN; j4 = jN;
        }
        // branchless drain: stages beyond NQ have all-false valid flags
        CONS(v0, as0, lo0, hi0);
        CONS(v1, as1, lo1, hi1);
        CONS(v2, as2, lo2, hi2);
    }
    // combine the 4 edge-groups
    s += __shfl_xor(s, 16, 64);
    s += __shfl_xor(s, 32, 64);
    #pragma unroll
    for (int p = 0; p < 8; ++p) {
        acc[p].x += __shfl_xor(acc[p].x, 16, 64);
        acc[p].x += __shfl_xor(acc[p].x, 32, 64);
        acc[p].y += __shfl_xor(acc[p].y, 16, 64);
        acc[p].y += __shfl_xor(acc[p].y, 32, 64);
    }
    float inv = 1.0f / (s + EPS_GAT);
    // group g writes features [f0 + g*4, f0 + g*4 + 4): pairs {2g, 2g+1}
    f32x2 p0 = (g & 2) ? ((g & 1) ? acc[6] : acc[4]) : ((g & 1) ? acc[2] : acc[0]);
    f32x2 p1 = (g & 2) ? ((g & 1) ? acc[7] : acc[5]) : ((g & 1) ? acc[3] : acc[1]);
    int fw = f0 + g * 4;
    float vv[4] = { p0.x, p0.y, p1.x, p1.y };
    ushort4 o;
    #pragma unroll
    for (int i = 0; i < 4; ++i) {
        float v = vv[i] * inv + b1[fw + i];
        v = v > 0.f ? v : expm1f(v);
        ((unsigned short*)&o)[i] = f2bf(v);
    }
    *(ushort4*)(hbf + (size_t)wid * 256 + fw) = o;
}

// ---- layer 2: 8 edges/wave, branchless 4-deep pipeline + log_softmax ------
// g = lane>>3 picks edge of octet; q = lane&7 holds classes [q*8, q*8+8)
__global__ __launch_bounds__(256, 6) void k_agg_l2(
        const unsigned short* __restrict__ xw2, const float* __restrict__ asrc,
        const float* __restrict__ adst, const unsigned* __restrict__ Menc,
        const float* __restrict__ b2, const int* __restrict__ rp,
        const int* __restrict__ ssrc, float* __restrict__ out, int N) {
    int wid = (blockIdx.x * 256 + threadIdx.x) >> 6;
    if (wid >= N) return;
    const int lane = threadIdx.x & 63;
    const int g  = lane >> 3;
    const int q  = lane & 7;
    const int f0 = q * 8;
    const float ad = adst[wid];
    const float m = lrelu(decf(Menc[0]) + ad);
    f32x2 acc[4];
    float s;
    {   // self loop counted on group 0 only
        float w = (g == 0) ? __expf(lrelu(asrc[wid] + ad) - m) : 0.0f;
        ushort8 xv = *(const ushort8*)(xw2 + (size_t)wid * 64 + f0);
        s = w;
        const unsigned* dx = (const unsigned*)&xv;
        #pragma unroll
        for (int p = 0; p < 4; ++p) {
            acc[p].x = w * __uint_as_float(dx[p] << 16);
            acc[p].y = w * __uint_as_float(dx[p] & 0xffff0000u);
        }
    }
    const int e0 = rp[wid], e1 = rp[wid + 1];
    if (e0 < e1) {
        const int NQ = (e1 - e0 + 7) >> 3;

        auto LDJ = [&](int base, int& j, bool& v) {
            v = base + g < e1;
            j = ssrc[min(base + g, e1 - 1)];
        };
        auto LDD = [&](int j, float& as, ushort8& xv) {
            as = asrc[j];
            xv = *(const ushort8*)(xw2 + ((size_t)j << 6) + f0);
        };
        auto CONS = [&](bool v, float as, const ushort8& xv) {
            float w = v ? __expf(lrelu(as + ad) - m) : 0.0f;
            s += w;
            f32x2 wp; wp.x = w; wp.y = w;
            const unsigned* dx = (const unsigned*)&xv;
            #pragma unroll
            for (int p = 0; p < 4; ++p) {
                f32x2 x;
                x.x = __uint_as_float(dx[p] << 16);
                x.y = __uint_as_float(dx[p] & 0xffff0000u);
                asm("v_pk_fma_f32 %0, %1, %2, %3"
                    : "=v"(acc[p]) : "v"(x), "v"(wp), "v"(acc[p]));
            }
        };

        int j0, j1, j2, j3; bool v0, v1, v2, v3;
        float as0, as1; ushort8 xv0, xv1;
        LDJ(e0,      j0, v0);
        LDJ(e0 + 8,  j1, v1);
        LDD(j0, as0, xv0);
        LDJ(e0 + 16, j2, v2);
        LDD(j1, as1, xv1);
        LDJ(e0 + 24, j3, v3);

        #pragma unroll 2
        for (int k = 0; k < NQ - 2; ++k) {
            int jN; bool vN;
            LDJ(e0 + 8 * k + 32, jN, vN);
            float as2; ushort8 xv2;
            LDD(j2, as2, xv2);
            CONS(v0, as0, xv0);
            v0 = v1; as0 = as1; xv0 = xv1;
            v1 = v2; as1 = as2; xv1 = xv2;
            v2 = v3; j2 = j3;
            v3 = vN; j3 = jN;
        }
        CONS(v0, as0, xv0);
        if (NQ >= 2) CONS(v1, as1, xv1);
    }
    // combine the 8 edge-groups (group id in lane bits 3..5)
    s += __shfl_xor(s, 8, 64);
    s += __shfl_xor(s, 16, 64);
    s += __shfl_xor(s, 32, 64);
    #pragma unroll
    for (int p = 0; p < 4; ++p) {
        acc[p].x += __shfl_xor(acc[p].x, 8, 64);
        acc[p].x += __shfl_xor(acc[p].x, 16, 64);
        acc[p].x += __shfl_xor(acc[p].x, 32, 64);
        acc[p].y += __shfl_xor(acc[p].y, 8, 64);
        acc[p].y += __shfl_xor(acc[p].y, 16, 64);
        acc[p].y += __shfl_xor(acc[p].y, 32, 64);
    }
    float inv = 1.0f / (s + EPS_GAT);
    float val[8];
    float mx = -1e30f;
    #pragma unroll
    for (int i = 0; i < 8; ++i) {
        float a = (i & 1) ? acc[i >> 1].y : acc[i >> 1].x;
        val[i] = a * inv + b2[f0 + i];
        mx = fmaxf(mx, val[i]);
    }
    // class reduce across q lanes (bits 0..2)
    #pragma unroll
    for (int off = 4; off > 0; off >>= 1) mx = fmaxf(mx, __shfl_xor(mx, off, 64));
    float sm = 0.f;
    #pragma unroll
    for (int i = 0; i < 8; ++i) sm += __expf(val[i] - mx);
    #pragma unroll
    for (int off = 4; off > 0; off >>= 1) sm += __shfl_xor(sm, off, 64);
    float lse = mx + logf(sm);
    if (g == 0) {
        float4 o0 = make_float4(val[0] - lse, val[1] - lse, val[2] - lse, val[3] - lse);
        float4 o1 = make_float4(val[4] - lse, val[5] - lse, val[6] - lse, val[7] - lse);
        *(float4*)(out + (size_t)wid * 64 + f0)     = o0;
        *(float4*)(out + (size_t)wid * 64 + f0 + 4) = o1;
    }
}

// ------------------------------- launcher ----------------------------------
static inline int cdiv(int a, int b) { return (a + b - 1) / b; }

extern "C" void kernel_launch(void* const* d_in, const int* in_sizes, int n_in,
                              void* d_out, int out_size, void* d_ws, size_t ws_size,
                              hipStream_t stream) {
    const float* x   = (const float*)d_in[0];
    const void*  eix = d_in[1];
    const float* W1  = (const float*)d_in[2];
    const float* as1 = (const float*)d_in[3];
    const float* ad1 = (const float*)d_in[4];
    const float* b1  = (const float*)d_in[5];
    const float* W2  = (const float*)d_in[6];
    const float* as2 = (const float*)d_in[7];
    const float* ad2 = (const float*)d_in[8];
    const float* b2  = (const float*)d_in[9];
    float* out = (float*)d_out;

    const int N = in_sizes[0] / 512;
    const int E = in_sizes[1] / 2;
    const int EB = cdiv(E, 256);
    const int WB = cdiv(512 * 256 + 256 * 64, 256);
    const int NB = cdiv(N, 256);
    const int NB1 = cdiv(N * 8, 256);
    const int NB2 = cdiv(N, 256);
    (void)n_in; (void)out_size; (void)ws_size;

    char* base = (char*)d_ws;
    size_t o = 0;
    auto alloc = [&](size_t bytes) -> char* {
        o = (o + 255) & ~(size_t)255;
        char* p = base + o;
        o += bytes;
        return p;
    };
    unsigned short* xw1b  = (unsigned short*)alloc((size_t)N * 256 * 2);
    unsigned short* hbf   = (unsigned short*)alloc((size_t)N * 256 * 2);
    unsigned short* xw2b  = (unsigned short*)alloc((size_t)N * 64 * 2);
    float*          asrc1 = (float*)alloc((size_t)N * 8 * 4);
    float*          adst1 = (float*)alloc((size_t)N * 8 * 4);
    float*          asrc2 = (float*)alloc((size_t)N * 4);
    float*          adst2 = (float*)alloc((size_t)N * 4);
    // zero region: Menc + counts contiguous, one memset
    size_t zero_begin = (o + 255) & ~(size_t)255;
    unsigned*       Menc  = (unsigned*)alloc(16 * 4);   // [0..7]=L1 heads, [8]=L2
    int*            counts= (int*)alloc((size_t)N * 4);
    size_t zero_end = o;
    int*            cursor= (int*)alloc((size_t)N * 4);
    int*            rowp  = (int*)alloc((size_t)(N + 1) * 4);
    int*            bsum  = (int*)alloc(256 * 4);
    int*            boff  = (int*)alloc(256 * 4);
    unsigned short* w1t   = (unsigned short*)alloc(512 * 256 * 2);
    unsigned short* w2t   = (unsigned short*)alloc(256 * 64 * 2);
    int*            ssrc  = (int*)alloc((size_t)E * 4);

    hipMemsetAsync(base + zero_begin, 0, zero_end - zero_begin, stream);

    // CSR build + weight prep folded into histogram grid
    k_hist_w<<<EB + WB, 256, 0, stream>>>(eix, counts, E, EB, W1, W2, w1t, w2t);
    k_scan1<<<NB, 256, 0, stream>>>(counts, rowp, bsum, N);
    k_scan2<<<1, 256, 0, stream>>>(bsum, boff, rowp + N, NB);
    k_scan3<<<NB, 256, 0, stream>>>(rowp, cursor, boff, N);
    k_fill<<<EB, 256, 0, stream>>>(eix, cursor, ssrc, E);

    // layer 1  (R7-proven tile shapes + T14 pipeline)
    k_gemm<128, 256, 512, true, true><<<cdiv(N, 128), 512, 0, stream>>>(x, w1t, xw1b, N, 512);
    k_alpha<<<NB1, 256, 0, stream>>>(xw1b, as1, ad1, asrc1, adst1, Menc, N * 8, 8, 32);
    k_agg_l1<<<cdiv(N * 64, 256), 256, 0, stream>>>(xw1b, asrc1, adst1, Menc, b1,
                                                    rowp, ssrc, hbf, N);
    // layer 2
    k_gemm<256, 64, 256, false, true><<<cdiv(N, 256), 256, 0, stream>>>(hbf, w2t, xw2b, N, 256);
    k_alpha<<<NB2, 256, 0, stream>>>(xw2b, as2, ad2, asrc2, adst2, Menc + 8, N, 1, 64);
    k_agg_l2<<<cdiv(N * 64, 256), 256, 0, stream>>>(xw2b, asrc2, adst2, Menc + 8, b2,
                                                    rowp, ssrc, out, N);
}